// Round 9
// baseline (483.472 us; speedup 1.0000x reference)
//
#include <hip/hip_runtime.h>
#include <hip/hip_bf16.h>
#include <stdint.h>

// SymbolicDecoder fused MLP evaluation, MI355X gfx950.  Round 9.
// Change vs round 8: faithful port of the proven 256^2 8-phase schedule
// (m201 template: 62% MfmaUtil at identical geometry).  Per K-tile (BK=64),
// 4 phases, each = {ds_read quadrant frags | 2-4 global_load_lds | barrier |
// lgkmcnt(0) | setprio(1) 16 MFMA setprio(0) | barrier}; counted vmcnt(4)
// ONCE per K-tile boundary (never 0 mid-loop).  Staging spread: B of t+1 at
// p0/p1, A of t+2 at p3 (into cur-A, freed after p2's reads).  Unrolled x2
// -> 8 phases/iter.  R8's coarse 32-MFMA subtile with 1 barrier serialized
// LDS and MFMA bursts at 1 block/CU -> 28% MfmaUtil across 3 structures.
// d_ws layout (ushorts): [0, 6291456) weights bf16 fragment-ready;
// [6291456, 35651584) feat bf16 natural [4096][7][1024].  Total 71.3 MB.

typedef __attribute__((ext_vector_type(4))) float f32x4;
typedef __attribute__((ext_vector_type(8))) short short8;
typedef __attribute__((ext_vector_type(8))) __bf16 bf16x8;

__device__ inline unsigned short f2bf(float f) {
  union { float f; uint32_t u; } x; x.f = f;
  uint32_t u = x.u;
  return (unsigned short)((u + 0x7fffu + ((u >> 16) & 1u)) >> 16);
}

// ---------------- out init: out[b][p][c] = b2(part(p))[c] ----------------
__global__ void init_out(float* __restrict__ out,
                         const float* __restrict__ sb2,
                         const float* __restrict__ db2) {
  int i = blockIdx.x * 256 + threadIdx.x;
  if (i >= 180224) return;
  int c = i & 1;
  int p = (i >> 1) % 22;
  float v;
  if (p < 3)       v = sb2[0 + c];
  else if (p == 3) v = sb2[2 + c];
  else if (p == 4) v = sb2[4 + c];
  else if (p < 19) v = db2[c];
  else             v = sb2[6 + c];
  out[i] = v;
}

// ---------------- weight prep: f32 -> bf16, fragment-ready layout --------
// Per (kstep64, coltile) 32KB tile, 16B chunk c2 = kk*1024+nblk*64+kgrp*16+j15
//   k = kstep*64 + kk*32 + kgrp*8 + e (e=0..7) ; j = coltile*256 + nblk*16 + j15
__global__ void prep_weights(const float* __restrict__ sw1,
                             const float* __restrict__ dw1,
                             unsigned short* __restrict__ wp) {
  int c = blockIdx.x * 256 + threadIdx.x;  // 786432 chunks total
  const float* W;
  size_t ob;
  int local;
  if (c < 524288) {
    int net = c >> 17;
    local = c & 131071;
    W = sw1 + (size_t)net * 1048576;
    ob = (size_t)net * 1048576;
  } else {
    local = c - 524288;
    W = dw1;
    ob = 4194304;
  }
  int c2 = local & 2047;
  int tile = local >> 11;
  int ct = tile & 3;
  int kstep = tile >> 2;
  int kk = c2 >> 10, nblk = (c2 >> 6) & 15, kgrp = (c2 >> 4) & 3, j15 = c2 & 15;
  int kb = kstep * 64 + kk * 32 + kgrp * 8;
  int j = ct * 256 + nblk * 16 + j15;
  short8 v;
#pragma unroll
  for (int e = 0; e < 8; e++) v[e] = (short)f2bf(W[(size_t)(kb + e) * 1024 + j]);
  *(short8*)(wp + ob + (size_t)local * 8) = v;
}

// ---------------- feat prep: f32 -> bf16, natural layout ----------------
__global__ void prep_feat(const float* __restrict__ feat,
                          unsigned short* __restrict__ fb) {
  int i = blockIdx.x * 256 + threadIdx.x;  // 3670016 chunks of 8
  const float* s = feat + (size_t)i * 8;
  f32x4 a = *(const f32x4*)s;
  f32x4 b = *(const f32x4*)(s + 4);
  short8 v;
  v[0] = (short)f2bf(a[0]); v[1] = (short)f2bf(a[1]);
  v[2] = (short)f2bf(a[2]); v[3] = (short)f2bf(a[3]);
  v[4] = (short)f2bf(b[0]); v[5] = (short)f2bf(b[1]);
  v[6] = (short)f2bf(b[2]); v[7] = (short)f2bf(b[3]);
  *(short8*)(fb + (size_t)i * 8) = v;
}

// ---------------- fused main: 256x256, BK=64, 8-phase schedule ----------
// LDS chunk layout per buffer (16B short8 idx): [kk(2)][tile16(16)][kg(4)][r15(16)]
//   A: row = tile16*16 + r15, k = kk*32 + kg*8 + e   (32 KB per buffer)
//   B: col = tile16*16 + r15, same k                 (32 KB per buffer)
// Fragment read: chunk = kk*1024 + tile16*64 + lane -> conflict-free.
__global__ __launch_bounds__(512, 2) void fused_main(
    const float* __restrict__ sb1, const float* __restrict__ sw2,
    const float* __restrict__ db1, const float* __restrict__ dw2,
    const unsigned short* __restrict__ wp,
    const unsigned short* __restrict__ fb, float* __restrict__ out) {
  __shared__ short8 Abuf0[2048];   // 32 KB each, 128 KB total
  __shared__ short8 Abuf1[2048];
  __shared__ short8 Bbuf0[2048];
  __shared__ short8 Bbuf1[2048];

  const int tid = threadIdx.x;
  const int lane = tid & 63;
  const int wid = tid >> 6;        // 0..7
  const int r15 = lane & 15;
  const int kg = lane >> 4;        // k-group 0..3
  const int wr = wid >> 2;         // wave row (0..1), 128 rows each
  const int wc = wid & 3;          // wave col (0..3), 64 cols each

  // Balanced per-XCD streams, T3 (32-tile) first for LPT scheduling.
  // 1408 blocks = 8 XCDs x 176: [0,112) T3 | [112,136) T0 | [136,144) T1 |
  // [144,152) T2 | [152,176) T4.  v counts ct-fastest within task.
  const int bid = blockIdx.x;
  const int x = bid & 7;
  const int j = bid >> 3;

  int task, NT, v;
  const unsigned short* wpt;
  const float* b1;
  const float* w2;
  if (j < 112)      { task = 3; v = x * 112 + j;        wpt = wp + 4194304; b1 = db1;        w2 = dw2;        NT = 32; }
  else if (j < 136) { task = 0; v = x * 24 + (j - 112); wpt = wp;           b1 = sb1;        w2 = sw2;        NT = 16; }
  else if (j < 144) { task = 1; v = x * 8 + (j - 136);  wpt = wp + 1048576; b1 = sb1 + 1024; w2 = sw2 + 2048; NT = 16; }
  else if (j < 152) { task = 2; v = x * 8 + (j - 144);  wpt = wp + 2097152; b1 = sb1 + 2048; w2 = sw2 + 4096; NT = 16; }
  else              { task = 4; v = x * 24 + (j - 152); wpt = wp + 3145728; b1 = sb1 + 3072; w2 = sw2 + 6144; NT = 16; }
  const int ct = v & 3;
  const int rbase = (v >> 2) * 256;

  // A staging pointers.  Thread (wid,lane) stages row-tiles mt=wid and
  // mt=wid+8: arow = rbase + mt*16 + r15, k-slice kg*8.  Two K-halves
  // (task 3 reads a slot pair) -> 4 pointers.
  const unsigned short *a00, *a01, *a10, *a11;
#pragma unroll
  for (int rs = 0; rs < 2; rs++) {
    int arow = rbase + (rs * 8 + wid) * 16 + r15;
    int ab, as1, as2;
    if (task == 0 || task == 4) {
      ab = arow / 3; int s = arow - ab * 3; as1 = s; as2 = s;
    } else if (task == 3) {
      ab = arow / 14; int pp = arow - ab * 14;
      if (pp < 12) { as1 = pp >> 2; as2 = 3 + (pp & 3); }
      else         { as1 = 4;       as2 = (pp == 12) ? 5 : 6; }
    } else {
      ab = arow; as1 = 6; as2 = 6;
    }
    const unsigned short* q0 = fb + ((size_t)ab * 7 + as1) * 1024 + kg * 8;
    const unsigned short* q1 = fb + ((size_t)ab * 7 + as2) * 1024 + kg * 8;
    if (rs == 0) { a00 = q0; a01 = q1; } else { a10 = q0; a11 = q1; }
  }

  f32x4 acc[8][4] = {};
  short8 afr[2][4], b0f[2][2], b1f[2][2];

#define GLL(SRC, BUF, BYTEOFF)                                                \
  __builtin_amdgcn_global_load_lds(                                          \
      (const __attribute__((address_space(1))) void*)(SRC),                  \
      (__attribute__((address_space(3))) void*)((char*)(BUF) + (BYTEOFF)),   \
      16, 0, 0)

  // A chunk of K-tile KS: 4 GLL (2 rowsets x 2 kk)
#define STAGE_A(KS, AB)                                                       \
  do {                                                                        \
    const int ko_ = ((KS) & 15) * 64;                                         \
    const unsigned short* r0_ = ((KS) < 16) ? a00 : a01;                      \
    const unsigned short* r1_ = ((KS) < 16) ? a10 : a11;                      \
    GLL(r0_ + ko_,      AB, wid * 1024);                                      \
    GLL(r1_ + ko_,      AB, 8192 + wid * 1024);                               \
    GLL(r0_ + ko_ + 32, AB, 16384 + wid * 1024);                              \
    GLL(r1_ + ko_ + 32, AB, 24576 + wid * 1024);                              \
  } while (0)

  // B kk0 half (2 GLL) and kk1 half (2 GLL) of K-tile KS
#define STAGE_B0(KS, BB)                                                      \
  do {                                                                        \
    const unsigned short* ws_ = wpt + (size_t)((KS) * 4 + ct) * 16384;        \
    GLL(ws_ + ((0 * 8 + wid) * 64 + lane) * 8, BB, (0 * 8 + wid) * 1024);     \
    GLL(ws_ + ((1 * 8 + wid) * 64 + lane) * 8, BB, (1 * 8 + wid) * 1024);     \
  } while (0)
#define STAGE_B1(KS, BB)                                                      \
  do {                                                                        \
    const unsigned short* ws_ = wpt + (size_t)((KS) * 4 + ct) * 16384;        \
    GLL(ws_ + ((2 * 8 + wid) * 64 + lane) * 8, BB, (2 * 8 + wid) * 1024);     \
    GLL(ws_ + ((3 * 8 + wid) * 64 + lane) * 8, BB, (3 * 8 + wid) * 1024);     \
  } while (0)

  // 16 MFMA: quadrant (MB..MB+3) x (NB..NB+1), both kk halves
#define MFMA16(AF, BF, MB, NB)                                                \
  do {                                                                        \
    _Pragma("unroll")                                                         \
    for (int kk_ = 0; kk_ < 2; kk_++)                                         \
      _Pragma("unroll")                                                       \
      for (int i_ = 0; i_ < 4; i_++)                                          \
        _Pragma("unroll")                                                     \
        for (int j_ = 0; j_ < 2; j_++)                                        \
          acc[(MB) + i_][(NB) + j_] = __builtin_amdgcn_mfma_f32_16x16x32_bf16(\
              __builtin_bit_cast(bf16x8, (AF)[kk_][i_]),                      \
              __builtin_bit_cast(bf16x8, (BF)[kk_][j_]),                      \
              acc[(MB) + i_][(NB) + j_], 0, 0, 0);                            \
  } while (0)

  // One K-tile (BK=64), 4 phases.  CA/CB = current buffers; NB = next B
  // buffer.  Staging: B-halves of T+1 at p0/p1 (into NB), A of T+2 at p3
  // (into CA, whose last read is p2).  Boundary: counted vmcnt(4) once.
#define TILE(T, CA, CB, NB)                                                   \
  do {                                                                        \
    /* ---- phase 0: read A[0..3],B[0..1]; stage B0(T+1); MFMA q(0,0) ---- */ \
    _Pragma("unroll")                                                         \
    for (int kk_ = 0; kk_ < 2; kk_++) {                                       \
      _Pragma("unroll")                                                       \
      for (int i_ = 0; i_ < 4; i_++)                                          \
        afr[kk_][i_] = (CA)[kk_ * 1024 + (wr * 8 + i_) * 64 + lane];          \
      _Pragma("unroll")                                                       \
      for (int j_ = 0; j_ < 2; j_++)                                          \
        b0f[kk_][j_] = (CB)[kk_ * 1024 + (wc * 4 + j_) * 64 + lane];          \
    }                                                                         \
    if ((T) + 1 < NT) STAGE_B0((T) + 1, NB);                                  \
    asm volatile("s_waitcnt lgkmcnt(8)" ::: "memory");                        \
    __builtin_amdgcn_s_barrier();                                             \
    asm volatile("s_waitcnt lgkmcnt(0)" ::: "memory");                        \
    __builtin_amdgcn_s_setprio(1);                                            \
    MFMA16(afr, b0f, 0, 0);                                                   \
    __builtin_amdgcn_s_setprio(0);                                            \
    __builtin_amdgcn_s_barrier();                                             \
    /* ---- phase 1: read B[2..3]; stage B1(T+1); MFMA q(0,1) ---- */         \
    _Pragma("unroll")                                                         \
    for (int kk_ = 0; kk_ < 2; kk_++)                                         \
      _Pragma("unroll")                                                       \
      for (int j_ = 0; j_ < 2; j_++)                                          \
        b1f[kk_][j_] = (CB)[kk_ * 1024 + (wc * 4 + 2 + j_) * 64 + lane];      \
    if ((T) + 1 < NT) STAGE_B1((T) + 1, NB);                                  \
    __builtin_amdgcn_s_barrier();                                             \
    asm volatile("s_waitcnt lgkmcnt(0)" ::: "memory");                        \
    __builtin_amdgcn_s_setprio(1);                                            \
    MFMA16(afr, b1f, 0, 2);                                                   \
    __builtin_amdgcn_s_setprio(0);                                            \
    __builtin_amdgcn_s_barrier();                                             \
    /* ---- phase 2: read A[4..7]; MFMA q(1,1) ---- */                        \
    _Pragma("unroll")                                                         \
    for (int kk_ = 0; kk_ < 2; kk_++)                                         \
      _Pragma("unroll")                                                       \
      for (int i_ = 0; i_ < 4; i_++)                                          \
        afr[kk_][i_] = (CA)[kk_ * 1024 + (wr * 8 + 4 + i_) * 64 + lane];      \
    __builtin_amdgcn_s_barrier();                                             \
    asm volatile("s_waitcnt lgkmcnt(0)" ::: "memory");                        \
    __builtin_amdgcn_s_setprio(1);                                            \
    MFMA16(afr, b1f, 4, 2);                                                   \
    __builtin_amdgcn_s_setprio(0);                                            \
    __builtin_amdgcn_s_barrier();                                             \
    /* ---- phase 3: stage A(T+2) into CA (freed); MFMA q(1,0) ---- */        \
    if ((T) + 2 < NT) STAGE_A((T) + 2, CA);                                   \
    __builtin_amdgcn_s_setprio(1);                                            \
    MFMA16(afr, b0f, 4, 0);                                                   \
    __builtin_amdgcn_s_setprio(0);                                            \
    /* ---- K-tile boundary: wait T+1's data (counted), sync ---- */          \
    if ((T) + 1 < NT) {                                                       \
      if ((T) + 2 < NT) asm volatile("s_waitcnt vmcnt(4)" ::: "memory");      \
      else              asm volatile("s_waitcnt vmcnt(0)" ::: "memory");      \
      __builtin_amdgcn_s_barrier();                                           \
    }                                                                         \
  } while (0)

  // prologue: tile0 complete (8) + tile1 A (4); wait tile0 -> vmcnt(4)
  STAGE_A(0, Abuf0);
  STAGE_B0(0, Bbuf0);
  STAGE_B1(0, Bbuf0);
  STAGE_A(1, Abuf1);
  asm volatile("s_waitcnt vmcnt(4)" ::: "memory");
  __builtin_amdgcn_s_barrier();

  for (int t = 0; t < NT; t += 2) {
    TILE(t,     Abuf0, Bbuf0, Bbuf1);
    TILE(t + 1, Abuf1, Bbuf1, Bbuf0);
  }
#undef TILE
#undef MFMA16
#undef STAGE_A
#undef STAGE_B0
#undef STAGE_B1
#undef GLL

  // ---- epilogue: h = relu(acc + b1); partial out = h . w2 ; atomicAdd ----
  float b1v[4], w20v[4], w21v[4];
#pragma unroll
  for (int n = 0; n < 4; n++) {
    int jj = ct * 256 + wc * 64 + n * 16 + r15;
    b1v[n] = b1[jj];
    w20v[n] = w2[2 * jj];
    w21v[n] = w2[2 * jj + 1];
  }
#pragma unroll
  for (int m = 0; m < 8; m++) {
#pragma unroll
    for (int r = 0; r < 4; r++) {
      float s0 = 0.f, s1 = 0.f;
#pragma unroll
      for (int n = 0; n < 4; n++) {
        float h = acc[m][n][r] + b1v[n];
        h = fmaxf(h, 0.f);
        s0 = fmaf(h, w20v[n], s0);
        s1 = fmaf(h, w21v[n], s1);
      }
#pragma unroll
      for (int off = 1; off < 16; off <<= 1) {
        s0 += __shfl_xor(s0, off, 64);
        s1 += __shfl_xor(s1, off, 64);
      }
      if (r15 == 0) {
        int rg = rbase + wr * 128 + m * 16 + (lane >> 4) * 4 + r;
        int b, p;
        if (task == 0)      { b = rg / 3;  p = rg - b * 3; }
        else if (task == 1) { b = rg;      p = 3; }
        else if (task == 2) { b = rg;      p = 4; }
        else if (task == 3) { b = rg / 14; p = 5 + (rg - b * 14); }
        else                { b = rg / 3;  p = 19 + (rg - b * 3); }
        atomicAdd(out + ((size_t)b * 44 + p * 2), s0);
        atomicAdd(out + ((size_t)b * 44 + p * 2 + 1), s1);
      }
    }
  }
}

extern "C" void kernel_launch(void* const* d_in, const int* in_sizes, int n_in,
                              void* d_out, int out_size, void* d_ws, size_t ws_size,
                              hipStream_t stream) {
  const float* feat = (const float*)d_in[0];
  const float* sw1  = (const float*)d_in[1];
  const float* sb1  = (const float*)d_in[2];
  const float* sw2  = (const float*)d_in[3];
  const float* sb2  = (const float*)d_in[4];
  const float* dw1  = (const float*)d_in[5];
  const float* db1  = (const float*)d_in[6];
  const float* dw2  = (const float*)d_in[7];
  const float* db2  = (const float*)d_in[8];
  float* out = (float*)d_out;
  unsigned short* wp = (unsigned short*)d_ws;      // 12.58 MB weights
  unsigned short* fb = wp + 6291456;               // 58.7 MB feat bf16

  init_out<<<704, 256, 0, stream>>>(out, sb2, db2);
  prep_weights<<<3072, 256, 0, stream>>>(sw1, dw1, wp);
  prep_feat<<<14336, 256, 0, stream>>>(feat, fb);
  // 1408 blocks = 8 XCD streams x 176 (112 T3 | 24 T0 | 8 T1 | 8 T2 | 24 T4)
  fused_main<<<1408, 512, 0, stream>>>(sb1, sw2, db1, dw2, wp, fb, out);
}